// Round 11
// baseline (275.433 us; speedup 1.0000x reference)
//
#include <hip/hip_runtime.h>
#include <hip/hip_bf16.h>

typedef __attribute__((ext_vector_type(8))) short short8;
typedef __attribute__((ext_vector_type(4))) float f32x4;
typedef __attribute__((ext_vector_type(4))) unsigned int u32x4;

#define D_DIM 512
#define Q_DIM 128
#define M_BLK 128   // rows per block (4 waves x 32 rows)
#define RT 2        // 16-row tiles per wave (32 rows)
#define CT 8        // 16-col tiles (all 128 queries)
#define KSTEP 64    // K per staged tile (256B contiguous per row)
#define NT (D_DIM / KSTEP)   // 8 staged tiles

// packed fp32x2 -> bf16x2 (RNE) via compiler-generated v_cvt_pk_bf16_f32
__device__ inline unsigned cvtpk2(float a, float b) {
    float2 t; t.x = a; t.y = b;
    __hip_bfloat162 h = __float22bfloat162_rn(t);
    unsigned u;
    __builtin_memcpy(&u, &h, 4);
    return u;
}

// scalar fp32 -> bf16 bits (RNE), used in prep only
__device__ inline unsigned short f2bf(float f) {
    union { float f; unsigned u; } v; v.f = f;
    unsigned r = v.u + 0x7fffu + ((v.u >> 16) & 1u);
    return (unsigned short)(r >> 16);
}

// One block per query qi: norms, threshold-tol, bf16-normalized query written
// in FRAGMENT-PACKED layout (R6's), out[qi] = -1 init (self-row exclusion;
// also makes the launch idempotent: rank_kernel only atomicAdds).
//
// Packed layout: B_p[((kblk*8 + c)*64 + kgrp*16 + lr)*8 + j]
//   = qn[c*16 + lr][kblk*32 + kgrp*8 + j]
// so rank_kernel's bfrag load is lane-contiguous 16B (1KB/wave-instr).
__global__ __launch_bounds__(256) void prep_kernel(
    const float* __restrict__ qs, const float* __restrict__ ts,
    unsigned short* __restrict__ qn_p, float* __restrict__ thr_adj,
    int* __restrict__ out)
{
    __shared__ float red[3][4];
    const int qi  = blockIdx.x;
    const int tid = threadIdx.x;
    const float* qrow = qs + qi * D_DIM;
    const float* trow = ts + qi * D_DIM;
    float sq = 0.f, st = 0.f, sqt = 0.f;
    for (int d = tid; d < D_DIM; d += 256) {
        float a = qrow[d], b = trow[d];
        sq += a * a; st += b * b; sqt += a * b;
    }
    #pragma unroll
    for (int off = 32; off > 0; off >>= 1) {
        sq  += __shfl_down(sq, off);
        st  += __shfl_down(st, off);
        sqt += __shfl_down(sqt, off);
    }
    const int wave = tid >> 6, lane = tid & 63;
    if (lane == 0) { red[0][wave] = sq; red[1][wave] = st; red[2][wave] = sqt; }
    __syncthreads();
    sq  = red[0][0] + red[0][1] + red[0][2] + red[0][3];
    st  = red[1][0] + red[1][1] + red[1][2] + red[1][3];
    sqt = red[2][0] + red[2][1] + red[2][2] + red[2][3];
    const float qnorm  = fmaxf(sqrtf(sq), 1e-12f);
    const float tnorm  = fmaxf(sqrtf(st), 1e-12f);
    const float thresh = sqt / (qnorm * tnorm);
    if (tid == 0) {
        // mask = (s >= thr) | (|s - thr| <= atol + rtol*|thr|)  ==  s >= thr - tol
        thr_adj[qi] = thresh - (1e-8f + 1e-5f * fabsf(thresh));
        out[qi] = -1;
    }
    const float inv = 1.0f / qnorm;
    const int c  = qi >> 4;      // 16-col tile index
    const int lr = qi & 15;      // col within tile
    for (int d = tid; d < D_DIM; d += 256) {
        const int kblk = d >> 5;         // which K32 block
        const int rem  = d & 31;
        const int kgrp = rem >> 3;       // 0..3
        const int j    = rem & 7;
        const size_t off = ((size_t)((kblk << 3) + c) * 64 + (kgrp << 4) + lr) * 8 + j;
        qn_p[off] = f2bf(qrow[d] * inv);
    }
}

// sims = data(N x 512) @ qn^T(512 x 128), counted against thr_adj per column.
// Per block: 128 rows, 4 waves, each wave owns 32 rows x all 128 cols.
// A is staged via global_load_lds into a double-buffered 2x32KB LDS tile
// (KSTEP=64 -> 256B contiguous per row per stage). The per-lane GLOBAL source
// address realizes the fragment layout; the LDS dest is linear (m104/m173).
// LDS compute reads are lane-contiguous ds_read_b128. B direct from L2
// (R6 packed layout). Loop: stage(next) -> compute(cur) -> syncthreads.
// Staging latency hides under compute + the co-resident 2nd block (m114).
// A-frag (16x32 bf16): lane l holds A[l&15][kgrp*8 + 0..7].
// C/D: col = lane&15, row = (lane>>4)*4 + j   [guide §3, m89-verified]
__global__ __launch_bounds__(256, 2) void rank_kernel(
    const float* __restrict__ data,
    const unsigned short* __restrict__ qn_p,
    const float* __restrict__ thr_adj,
    int* __restrict__ out, int N)
{
    // [buf][wave][rt][kblk][q][64 lanes x 4 floats] = 64KB
    __shared__ float albuf[2][4][RT][2][2][256];
    __shared__ int cnt_lds[Q_DIM];

    const int tid  = threadIdx.x;
    const int lane = tid & 63;
    const int wave = tid >> 6;
    const int lr   = lane & 15;   // A row / B col within 16-tile
    const int kgrp = lane >> 4;   // 0..3
    const int row0 = blockIdx.x * M_BLK + wave * 32;

    for (int i = tid; i < Q_DIM; i += 256) cnt_lds[i] = 0;

    f32x4 acc[RT][CT] = {};

    // per-lane global staging base: row (clamped) + kgrp sub-chunk
    const float* abase[RT];
    #pragma unroll
    for (int rt = 0; rt < RT; ++rt) {
        int r = row0 + rt * 16 + lr;
        if (r > N - 1) r = N - 1;   // clamp tail loads; masked at count
        abase[rt] = data + (size_t)r * D_DIM + kgrp * 8;
    }
    // per-lane base into packed B: + lane*8 shorts (16B)
    const unsigned short* bbase = qn_p + (size_t)lane * 8;

    // stage tile tt into buffer nb: 8 x global_load_lds(16B/lane = 1KB/instr)
    auto stage = [&](int nb, int tt) {
        const int kb = tt * KSTEP;
        #pragma unroll
        for (int rt = 0; rt < RT; ++rt)
            #pragma unroll
            for (int kk = 0; kk < 2; ++kk)
                #pragma unroll
                for (int q = 0; q < 2; ++q)
                    __builtin_amdgcn_global_load_lds(
                        (const __attribute__((address_space(1))) unsigned int*)
                            (abase[rt] + kb + kk * 32 + q * 4),
                        (__attribute__((address_space(3))) unsigned int*)
                            &albuf[nb][wave][rt][kk][q][0],
                        16, 0, 0);
    };

    stage(0, 0);
    __syncthreads();   // staging drained (vmcnt0) + cnt_lds init visible

    int cur = 0;
    #pragma unroll 1
    for (int t = 0; t < NT; ++t) {
        if (t + 1 < NT) stage(cur ^ 1, t + 1);   // async prefetch next tile
        #pragma unroll
        for (int kk = 0; kk < 2; ++kk) {
            const int gk = t * 2 + kk;           // global K32 block index
            // B fragments — packed, lane-contiguous 16B (1KB per wave instr)
            short8 bfrag[CT];
            #pragma unroll
            for (int c = 0; c < CT; ++c)
                bfrag[c] = *(const short8*)(bbase + (size_t)((gk << 3) + c) * 512);
            // A fragments from LDS + cvt
            short8 af[RT];
            #pragma unroll
            for (int rt = 0; rt < RT; ++rt) {
                const float* ap = &albuf[cur][wave][rt][kk][0][lane << 2];
                f32x4 a0 = *(const f32x4*)ap;          // k = kgrp*8 + 0..3
                f32x4 a1 = *(const f32x4*)(ap + 256);  // k = kgrp*8 + 4..7
                u32x4 p;
                p[0] = cvtpk2(a0[0], a0[1]);
                p[1] = cvtpk2(a0[2], a0[3]);
                p[2] = cvtpk2(a1[0], a1[1]);
                p[3] = cvtpk2(a1[2], a1[3]);
                __builtin_memcpy(&af[rt], &p, 16);
            }
            // MFMA
            #pragma unroll
            for (int c = 0; c < CT; ++c)
                #pragma unroll
                for (int rt = 0; rt < RT; ++rt)
                    acc[rt][c] = __builtin_amdgcn_mfma_f32_16x16x32_bf16(
                        af[rt], bfrag[c], acc[rt][c], 0, 0, 0);
        }
        __syncthreads();   // stage(next) drained + everyone done reading cur
        cur ^= 1;
    }

    // count sims >= thr per column, reduce across the wave's 4 k-groups
    const bool full = (row0 + 32 <= N);
    #pragma unroll
    for (int c = 0; c < CT; ++c) {
        const float thr = thr_adj[c * 16 + lr];
        int cnt = 0;
        if (full) {
            #pragma unroll
            for (int rt = 0; rt < RT; ++rt)
                #pragma unroll
                for (int j = 0; j < 4; ++j)
                    cnt += (acc[rt][c][j] >= thr) ? 1 : 0;
        } else {
            #pragma unroll
            for (int rt = 0; rt < RT; ++rt)
                #pragma unroll
                for (int j = 0; j < 4; ++j) {
                    int grow = row0 + rt * 16 + kgrp * 4 + j;
                    if (grow < N && acc[rt][c][j] >= thr) cnt++;
                }
        }
        cnt += __shfl_xor(cnt, 16);
        cnt += __shfl_xor(cnt, 32);
        if (lane < 16) atomicAdd(&cnt_lds[c * 16 + lr], cnt);
    }
    __syncthreads();
    for (int i = tid; i < Q_DIM; i += 256) {
        atomicAdd(&out[i], cnt_lds[i]);
    }
}

extern "C" void kernel_launch(void* const* d_in, const int* in_sizes, int n_in,
                              void* d_out, int out_size, void* d_ws, size_t ws_size,
                              hipStream_t stream)
{
    const float* data    = (const float*)d_in[0];
    const float* queries = (const float*)d_in[1];
    const float* truths  = (const float*)d_in[2];
    const int N = in_sizes[0] / D_DIM;

    unsigned short* qn_p = (unsigned short*)d_ws;
    float*          thr  = (float*)((char*)d_ws + (size_t)Q_DIM * D_DIM * sizeof(unsigned short));
    int*            out  = (int*)d_out;

    prep_kernel<<<Q_DIM, 256, 0, stream>>>(queries, truths, qn_p, thr, out);

    const int nblk = (N + M_BLK - 1) / M_BLK;
    rank_kernel<<<nblk, 256, 0, stream>>>(data, qn_p, thr, out, N);
}

// Round 12
// 244.091 us; speedup vs baseline: 1.1284x; 1.1284x over previous
//
#include <hip/hip_runtime.h>
#include <hip/hip_bf16.h>

typedef __attribute__((ext_vector_type(8))) short short8;
typedef __attribute__((ext_vector_type(4))) float f32x4;
typedef __attribute__((ext_vector_type(4))) unsigned int u32x4;

#define D_DIM 512
#define Q_DIM 128
#define M_BLK 256   // rows per block (4 waves x 64 rows)
#define RT 4        // 16-row tiles per wave (64 rows)
#define CT 8        // 16-col tiles (all 128 queries)

// packed fp32x2 -> bf16x2 (RNE) via compiler-generated v_cvt_pk_bf16_f32
__device__ inline unsigned cvtpk2(float a, float b) {
    float2 t; t.x = a; t.y = b;
    __hip_bfloat162 h = __float22bfloat162_rn(t);
    unsigned u;
    __builtin_memcpy(&u, &h, 4);
    return u;
}

// scalar fp32 -> bf16 bits (RNE), used in prep only
__device__ inline unsigned short f2bf(float f) {
    union { float f; unsigned u; } v; v.f = f;
    unsigned r = v.u + 0x7fffu + ((v.u >> 16) & 1u);
    return (unsigned short)(r >> 16);
}

// One block per query qi: norms, threshold-tol, bf16-normalized query written
// in FRAGMENT-PACKED layout (R6's), out[qi] = -1 init (self-row exclusion;
// also makes the launch idempotent: rank_kernel only atomicAdds).
//
// Packed layout: B_p[((kblk*8 + c)*64 + kgrp*16 + lr)*8 + j]
//   = qn[c*16 + lr][kblk*32 + kgrp*8 + j]
// so rank_kernel's bfrag load is lane-contiguous 16B (1KB/wave-instr).
__global__ __launch_bounds__(256) void prep_kernel(
    const float* __restrict__ qs, const float* __restrict__ ts,
    unsigned short* __restrict__ qn_p, float* __restrict__ thr_adj,
    int* __restrict__ out)
{
    __shared__ float red[3][4];
    const int qi  = blockIdx.x;
    const int tid = threadIdx.x;
    const float* qrow = qs + qi * D_DIM;
    const float* trow = ts + qi * D_DIM;
    float sq = 0.f, st = 0.f, sqt = 0.f;
    for (int d = tid; d < D_DIM; d += 256) {
        float a = qrow[d], b = trow[d];
        sq += a * a; st += b * b; sqt += a * b;
    }
    #pragma unroll
    for (int off = 32; off > 0; off >>= 1) {
        sq  += __shfl_down(sq, off);
        st  += __shfl_down(st, off);
        sqt += __shfl_down(sqt, off);
    }
    const int wave = tid >> 6, lane = tid & 63;
    if (lane == 0) { red[0][wave] = sq; red[1][wave] = st; red[2][wave] = sqt; }
    __syncthreads();
    sq  = red[0][0] + red[0][1] + red[0][2] + red[0][3];
    st  = red[1][0] + red[1][1] + red[1][2] + red[1][3];
    sqt = red[2][0] + red[2][1] + red[2][2] + red[2][3];
    const float qnorm  = fmaxf(sqrtf(sq), 1e-12f);
    const float tnorm  = fmaxf(sqrtf(st), 1e-12f);
    const float thresh = sqt / (qnorm * tnorm);
    if (tid == 0) {
        // mask = (s >= thr) | (|s - thr| <= atol + rtol*|thr|)  ==  s >= thr - tol
        thr_adj[qi] = thresh - (1e-8f + 1e-5f * fabsf(thresh));
        out[qi] = -1;
    }
    const float inv = 1.0f / qnorm;
    const int c  = qi >> 4;      // 16-col tile index
    const int lr = qi & 15;      // col within tile
    for (int d = tid; d < D_DIM; d += 256) {
        const int kblk = d >> 5;         // which K32 block
        const int rem  = d & 31;
        const int kgrp = rem >> 3;       // 0..3
        const int j    = rem & 7;
        const size_t off = ((size_t)((kblk << 3) + c) * 64 + (kgrp << 4) + lr) * 8 + j;
        qn_p[off] = f2bf(qrow[d] * inv);
    }
}

// sims = data(N x 512) @ qn^T(512 x 128), counted against thr_adj per column.
// Per block: 256 rows, 4 waves, each wave owns 64 rows x all 128 cols.
// KSTEP=64: each K-step reads 256B CONTIGUOUS per row (4 cache lines).
// No barriers in the K-loop -> waves run at independent phases; s_setprio(1)
// around the MFMA clusters lets the CU scheduler favor MFMA-entering waves
// while others issue VMEM (T5 regime, m191). unroll 2 gives the compiler
// two steps of visibility to interleave next-step loads under MFMAs.
// In-step order: 16 A-loads -> 8 B-lo -> cvt(A) -> 8 B-hi -> MFMA h0 -> h1.
// A-frag (16x32 bf16): lane l holds A[l&15][h*32 + (l>>4)*8 + 0..7].
// B-frag: packed layout, lane-contiguous 16B per (kblk, c).
// C/D: col = lane&15, row = (lane>>4)*4 + j   [guide §3, m89-verified]
__global__ __launch_bounds__(256, 2) void rank_kernel(
    const float* __restrict__ data,
    const unsigned short* __restrict__ qn_p,
    const float* __restrict__ thr_adj,
    int* __restrict__ out, int N)
{
    __shared__ int cnt_lds[Q_DIM];
    const int tid  = threadIdx.x;
    const int lane = tid & 63;
    const int wave = tid >> 6;
    const int lr   = lane & 15;   // A row / B col within 16-tile
    const int kgrp = lane >> 4;   // 0..3
    const int row0 = blockIdx.x * M_BLK + wave * 64;

    for (int i = tid; i < Q_DIM; i += 256) cnt_lds[i] = 0;
    __syncthreads();

    f32x4 acc[RT][CT] = {};

    const float* aptr[RT];
    #pragma unroll
    for (int rt = 0; rt < RT; ++rt) {
        int r = row0 + rt * 16 + lr;
        if (r > N - 1) r = N - 1;   // clamp tail loads; masked at count
        aptr[rt] = data + (size_t)r * D_DIM + kgrp * 8;
    }
    // per-lane base into packed B: + lane*8 shorts (16B)
    const unsigned short* bbase = qn_p + (size_t)lane * 8;

    #pragma unroll 2
    for (int t = 0; t < D_DIM / 64; ++t) {
        const int kb = t * 64;
        // 1. issue all 16 A loads (256B contiguous per row)
        f32x4 ca[RT][4];
        #pragma unroll
        for (int rt = 0; rt < RT; ++rt) {
            const f32x4* p = (const f32x4*)(aptr[rt] + kb);
            ca[rt][0] = p[0];   // h=0, lo
            ca[rt][1] = p[1];   // h=0, hi
            ca[rt][2] = p[8];   // h=1, lo
            ca[rt][3] = p[9];   // h=1, hi
        }
        // 2. issue B-lo (kblk = 2t) — flies while cvt waits on A
        short8 bflo[CT];
        #pragma unroll
        for (int c = 0; c < CT; ++c)
            bflo[c] = *(const short8*)(bbase + (size_t)(((2 * t) << 3) + c) * 512);
        // 3. convert A -> two K32 fragments per rt (ca dies here)
        short8 af0[RT], af1[RT];
        #pragma unroll
        for (int rt = 0; rt < RT; ++rt) {
            u32x4 p0, p1;
            p0[0] = cvtpk2(ca[rt][0][0], ca[rt][0][1]);
            p0[1] = cvtpk2(ca[rt][0][2], ca[rt][0][3]);
            p0[2] = cvtpk2(ca[rt][1][0], ca[rt][1][1]);
            p0[3] = cvtpk2(ca[rt][1][2], ca[rt][1][3]);
            p1[0] = cvtpk2(ca[rt][2][0], ca[rt][2][1]);
            p1[1] = cvtpk2(ca[rt][2][2], ca[rt][2][3]);
            p1[2] = cvtpk2(ca[rt][3][0], ca[rt][3][1]);
            p1[3] = cvtpk2(ca[rt][3][2], ca[rt][3][3]);
            __builtin_memcpy(&af0[rt], &p0, 16);
            __builtin_memcpy(&af1[rt], &p1, 16);
        }
        // 4. issue B-hi (kblk = 2t+1) — flies under h0's MFMAs
        short8 bfhi[CT];
        #pragma unroll
        for (int c = 0; c < CT; ++c)
            bfhi[c] = *(const short8*)(bbase + (size_t)(((2 * t + 1) << 3) + c) * 512);
        // 5. MFMA h=0 and h=1 under raised wave priority (T5)
        __builtin_amdgcn_s_setprio(1);
        #pragma unroll
        for (int c = 0; c < CT; ++c)
            #pragma unroll
            for (int rt = 0; rt < RT; ++rt)
                acc[rt][c] = __builtin_amdgcn_mfma_f32_16x16x32_bf16(
                    af0[rt], bflo[c], acc[rt][c], 0, 0, 0);
        #pragma unroll
        for (int c = 0; c < CT; ++c)
            #pragma unroll
            for (int rt = 0; rt < RT; ++rt)
                acc[rt][c] = __builtin_amdgcn_mfma_f32_16x16x32_bf16(
                    af1[rt], bfhi[c], acc[rt][c], 0, 0, 0);
        __builtin_amdgcn_s_setprio(0);
    }

    // count sims >= thr per column, reduce across the wave's 4 k-groups
    const bool full = (row0 + 64 <= N);
    #pragma unroll
    for (int c = 0; c < CT; ++c) {
        const float thr = thr_adj[c * 16 + lr];
        int cnt = 0;
        if (full) {
            #pragma unroll
            for (int rt = 0; rt < RT; ++rt)
                #pragma unroll
                for (int j = 0; j < 4; ++j)
                    cnt += (acc[rt][c][j] >= thr) ? 1 : 0;
        } else {
            #pragma unroll
            for (int rt = 0; rt < RT; ++rt)
                #pragma unroll
                for (int j = 0; j < 4; ++j) {
                    int grow = row0 + rt * 16 + kgrp * 4 + j;
                    if (grow < N && acc[rt][c][j] >= thr) cnt++;
                }
        }
        cnt += __shfl_xor(cnt, 16);
        cnt += __shfl_xor(cnt, 32);
        if (lane < 16) atomicAdd(&cnt_lds[c * 16 + lr], cnt);
    }
    __syncthreads();
    for (int i = tid; i < Q_DIM; i += 256) {
        atomicAdd(&out[i], cnt_lds[i]);
    }
}

extern "C" void kernel_launch(void* const* d_in, const int* in_sizes, int n_in,
                              void* d_out, int out_size, void* d_ws, size_t ws_size,
                              hipStream_t stream)
{
    const float* data    = (const float*)d_in[0];
    const float* queries = (const float*)d_in[1];
    const float* truths  = (const float*)d_in[2];
    const int N = in_sizes[0] / D_DIM;

    unsigned short* qn_p = (unsigned short*)d_ws;
    float*          thr  = (float*)((char*)d_ws + (size_t)Q_DIM * D_DIM * sizeof(unsigned short));
    int*            out  = (int*)d_out;

    prep_kernel<<<Q_DIM, 256, 0, stream>>>(queries, truths, qn_p, thr, out);

    const int nblk = (N + M_BLK - 1) / M_BLK;
    rank_kernel<<<nblk, 256, 0, stream>>>(data, qn_p, thr, out, N);
}

// Round 13
// 214.389 us; speedup vs baseline: 1.2847x; 1.1385x over previous
//
#include <hip/hip_runtime.h>
#include <hip/hip_bf16.h>

typedef __attribute__((ext_vector_type(8))) short short8;
typedef __attribute__((ext_vector_type(4))) float f32x4;
typedef __attribute__((ext_vector_type(4))) unsigned int u32x4;

#define D_DIM 512
#define Q_DIM 128
#define M_BLK 256   // rows per block (4 waves x 64 rows)
#define RT 4        // 16-row tiles per wave (64 rows)
#define CT 8        // 16-col tiles (all 128 queries)

// packed fp32x2 -> bf16x2 (RNE) via compiler-generated v_cvt_pk_bf16_f32
__device__ inline unsigned cvtpk2(float a, float b) {
    float2 t; t.x = a; t.y = b;
    __hip_bfloat162 h = __float22bfloat162_rn(t);
    unsigned u;
    __builtin_memcpy(&u, &h, 4);
    return u;
}

// scalar fp32 -> bf16 bits (RNE), used in prep only
__device__ inline unsigned short f2bf(float f) {
    union { float f; unsigned u; } v; v.f = f;
    unsigned r = v.u + 0x7fffu + ((v.u >> 16) & 1u);
    return (unsigned short)(r >> 16);
}

// One block per query qi: norms, threshold-tol, bf16-normalized query written
// in FRAGMENT-PACKED layout (R6's), out[qi] = -1 init (self-row exclusion;
// also makes the launch idempotent: rank_kernel only atomicAdds).
//
// Packed layout: B_p[((kblk*8 + c)*64 + kgrp*16 + lr)*8 + j]
//   = qn[c*16 + lr][kblk*32 + kgrp*8 + j]
// so rank_kernel's bfrag load is lane-contiguous 16B (1KB/wave-instr).
__global__ __launch_bounds__(256) void prep_kernel(
    const float* __restrict__ qs, const float* __restrict__ ts,
    unsigned short* __restrict__ qn_p, float* __restrict__ thr_adj,
    int* __restrict__ out)
{
    __shared__ float red[3][4];
    const int qi  = blockIdx.x;
    const int tid = threadIdx.x;
    const float* qrow = qs + qi * D_DIM;
    const float* trow = ts + qi * D_DIM;
    float sq = 0.f, st = 0.f, sqt = 0.f;
    for (int d = tid; d < D_DIM; d += 256) {
        float a = qrow[d], b = trow[d];
        sq += a * a; st += b * b; sqt += a * b;
    }
    #pragma unroll
    for (int off = 32; off > 0; off >>= 1) {
        sq  += __shfl_down(sq, off);
        st  += __shfl_down(st, off);
        sqt += __shfl_down(sqt, off);
    }
    const int wave = tid >> 6, lane = tid & 63;
    if (lane == 0) { red[0][wave] = sq; red[1][wave] = st; red[2][wave] = sqt; }
    __syncthreads();
    sq  = red[0][0] + red[0][1] + red[0][2] + red[0][3];
    st  = red[1][0] + red[1][1] + red[1][2] + red[1][3];
    sqt = red[2][0] + red[2][1] + red[2][2] + red[2][3];
    const float qnorm  = fmaxf(sqrtf(sq), 1e-12f);
    const float tnorm  = fmaxf(sqrtf(st), 1e-12f);
    const float thresh = sqt / (qnorm * tnorm);
    if (tid == 0) {
        // mask = (s >= thr) | (|s - thr| <= atol + rtol*|thr|)  ==  s >= thr - tol
        thr_adj[qi] = thresh - (1e-8f + 1e-5f * fabsf(thresh));
        out[qi] = -1;
    }
    const float inv = 1.0f / qnorm;
    const int c  = qi >> 4;      // 16-col tile index
    const int lr = qi & 15;      // col within tile
    for (int d = tid; d < D_DIM; d += 256) {
        const int kblk = d >> 5;         // which K32 block
        const int rem  = d & 31;
        const int kgrp = rem >> 3;       // 0..3
        const int j    = rem & 7;
        const size_t off = ((size_t)((kblk << 3) + c) * 64 + (kgrp << 4) + lr) * 8 + j;
        qn_p[off] = f2bf(qrow[d] * inv);
    }
}

// sims = data(N x 512) @ qn^T(512 x 128), counted against thr_adj per column.
// Per block: 256 rows, 4 waves, each wave owns 64 rows x all 128 cols.
// KSTEP=64: each K-step reads 256B CONTIGUOUS per row (4 cache lines) for
// HBM page locality. Two K32 MFMA halves per step. No K-loop barriers.
// In-step order: 16 A-loads -> 8 B-lo -> cvt(A) -> 8 B-hi -> MFMA h0 -> h1,
// so B-lo flies under cvt and B-hi under h0's MFMAs.
// A-frag (16x32 bf16): lane l holds A[l&15][h*32 + (l>>4)*8 + 0..7].
// B-frag: packed layout, lane-contiguous 16B per (kblk, c).
// C/D: col = lane&15, row = (lane>>4)*4 + j   [guide §3, m89-verified]
__global__ __launch_bounds__(256, 2) void rank_kernel(
    const float* __restrict__ data,
    const unsigned short* __restrict__ qn_p,
    const float* __restrict__ thr_adj,
    int* __restrict__ out, int N)
{
    __shared__ int cnt_lds[Q_DIM];
    const int tid  = threadIdx.x;
    const int lane = tid & 63;
    const int wave = tid >> 6;
    const int lr   = lane & 15;   // A row / B col within 16-tile
    const int kgrp = lane >> 4;   // 0..3
    const int row0 = blockIdx.x * M_BLK + wave * 64;

    for (int i = tid; i < Q_DIM; i += 256) cnt_lds[i] = 0;
    __syncthreads();

    f32x4 acc[RT][CT] = {};

    const float* aptr[RT];
    #pragma unroll
    for (int rt = 0; rt < RT; ++rt) {
        int r = row0 + rt * 16 + lr;
        if (r > N - 1) r = N - 1;   // clamp tail loads; masked at count
        aptr[rt] = data + (size_t)r * D_DIM + kgrp * 8;
    }
    // per-lane base into packed B: + lane*8 shorts (16B)
    const unsigned short* bbase = qn_p + (size_t)lane * 8;

    #pragma unroll 1
    for (int t = 0; t < D_DIM / 64; ++t) {
        const int kb = t * 64;
        // 1. issue all 16 A loads (256B contiguous per row across the step)
        float4 ca[RT][4];
        #pragma unroll
        for (int rt = 0; rt < RT; ++rt) {
            const float* p = aptr[rt] + kb;
            ca[rt][0] = *(const float4*)(p);        // h=0, lo
            ca[rt][1] = *(const float4*)(p + 4);    // h=0, hi
            ca[rt][2] = *(const float4*)(p + 32);   // h=1, lo
            ca[rt][3] = *(const float4*)(p + 36);   // h=1, hi
        }
        // 2. issue B-lo (kblk = 2t) — flies while cvt waits on A
        short8 bflo[CT];
        #pragma unroll
        for (int c = 0; c < CT; ++c)
            bflo[c] = *(const short8*)(bbase + (size_t)(((2 * t) << 3) + c) * 512);
        // 3. convert A -> two K32 fragments per rt (ca dies here)
        short8 af0[RT], af1[RT];
        #pragma unroll
        for (int rt = 0; rt < RT; ++rt) {
            u32x4 p0, p1;
            p0[0] = cvtpk2(ca[rt][0].x, ca[rt][0].y);
            p0[1] = cvtpk2(ca[rt][0].z, ca[rt][0].w);
            p0[2] = cvtpk2(ca[rt][1].x, ca[rt][1].y);
            p0[3] = cvtpk2(ca[rt][1].z, ca[rt][1].w);
            p1[0] = cvtpk2(ca[rt][2].x, ca[rt][2].y);
            p1[1] = cvtpk2(ca[rt][2].z, ca[rt][2].w);
            p1[2] = cvtpk2(ca[rt][3].x, ca[rt][3].y);
            p1[3] = cvtpk2(ca[rt][3].z, ca[rt][3].w);
            __builtin_memcpy(&af0[rt], &p0, 16);
            __builtin_memcpy(&af1[rt], &p1, 16);
        }
        // 4. issue B-hi (kblk = 2t+1) — flies under h0's MFMAs
        short8 bfhi[CT];
        #pragma unroll
        for (int c = 0; c < CT; ++c)
            bfhi[c] = *(const short8*)(bbase + (size_t)(((2 * t + 1) << 3) + c) * 512);
        // 5. MFMA h=0
        #pragma unroll
        for (int c = 0; c < CT; ++c)
            #pragma unroll
            for (int rt = 0; rt < RT; ++rt)
                acc[rt][c] = __builtin_amdgcn_mfma_f32_16x16x32_bf16(
                    af0[rt], bflo[c], acc[rt][c], 0, 0, 0);
        // 6. MFMA h=1
        #pragma unroll
        for (int c = 0; c < CT; ++c)
            #pragma unroll
            for (int rt = 0; rt < RT; ++rt)
                acc[rt][c] = __builtin_amdgcn_mfma_f32_16x16x32_bf16(
                    af1[rt], bfhi[c], acc[rt][c], 0, 0, 0);
    }

    // count sims >= thr per column, reduce across the wave's 4 k-groups
    const bool full = (row0 + 64 <= N);
    #pragma unroll
    for (int c = 0; c < CT; ++c) {
        const float thr = thr_adj[c * 16 + lr];
        int cnt = 0;
        if (full) {
            #pragma unroll
            for (int rt = 0; rt < RT; ++rt)
                #pragma unroll
                for (int j = 0; j < 4; ++j)
                    cnt += (acc[rt][c][j] >= thr) ? 1 : 0;
        } else {
            #pragma unroll
            for (int rt = 0; rt < RT; ++rt)
                #pragma unroll
                for (int j = 0; j < 4; ++j) {
                    int grow = row0 + rt * 16 + kgrp * 4 + j;
                    if (grow < N && acc[rt][c][j] >= thr) cnt++;
                }
        }
        cnt += __shfl_xor(cnt, 16);
        cnt += __shfl_xor(cnt, 32);
        if (lane < 16) atomicAdd(&cnt_lds[c * 16 + lr], cnt);
    }
    __syncthreads();
    for (int i = tid; i < Q_DIM; i += 256) {
        atomicAdd(&out[i], cnt_lds[i]);
    }
}

extern "C" void kernel_launch(void* const* d_in, const int* in_sizes, int n_in,
                              void* d_out, int out_size, void* d_ws, size_t ws_size,
                              hipStream_t stream)
{
    const float* data    = (const float*)d_in[0];
    const float* queries = (const float*)d_in[1];
    const float* truths  = (const float*)d_in[2];
    const int N = in_sizes[0] / D_DIM;

    unsigned short* qn_p = (unsigned short*)d_ws;
    float*          thr  = (float*)((char*)d_ws + (size_t)Q_DIM * D_DIM * sizeof(unsigned short));
    int*            out  = (int*)d_out;

    prep_kernel<<<Q_DIM, 256, 0, stream>>>(queries, truths, qn_p, thr, out);

    const int nblk = (N + M_BLK - 1) / M_BLK;
    rank_kernel<<<nblk, 256, 0, stream>>>(data, qn_p, thr, out, N);
}